// Round 5
// baseline (289.027 us; speedup 1.0000x reference)
//
#include <hip/hip_runtime.h>
#include <hip/hip_fp8.h>

// CausalConv3dFP8 round 5: T14 async-STAGE split (prefetch next cc-chunk into regs
// under the MFMA phase; raw s_barrier + lgkmcnt-only drain so vmcnt stays in flight).
// xq global layout: [b][d4][hp194][ci8 16][wp322][8B]
// wpk layout:       [tap27][ci8 16][wv4][l15 16][mf2][8B]

using f32x4 = __attribute__((ext_vector_type(4))) float;
typedef long long i64;
struct alignas(16) L2v { i64 x, y; };

namespace {
constexpr int Cc = 128, Dd = 4, Hh = 192, Ww = 320;
constexpr int HP = 194, WP = 322;
constexpr int NTAP = 27;
constexpr size_t PLANE = (size_t)16 * WP * 8;              // 41,216 B per (b,d,h) row-plane
constexpr size_t XQ_BYTES = (size_t)2 * Dd * HP * PLANE;   // 63,967,232
constexpr int ZA = 8 * 2 * 2576;
constexpr int ZB = 8 * 192 * 32;
constexpr int NLD = 7;                                     // ceil(1584/256)
constexpr int CCSTEP = 4 * WP * 8;                         // per-cc global offset (10,304 B)
}

__global__ __launch_bounds__(256) void zero_pad_kernel(unsigned char* __restrict__ xq) {
  int i = blockIdx.x * 256 + threadIdx.x;
  if (i < ZA) {
    int bd = i / (2 * 2576);
    int r = i - bd * (2 * 2576);
    int hsel = r / 2576, seg = r - hsel * 2576;
    L2v z{0, 0};
    *(L2v*)(xq + ((size_t)bd * HP + (hsel ? 193 : 0)) * PLANE + (size_t)seg * 16) = z;
  } else if (i < ZA + ZB) {
    int j = i - ZA;
    int bd = j / (192 * 32);
    int r = j - bd * (192 * 32);
    int h = r / 32 + 1;
    int t = r & 31;
    int g = t >> 1, wsel = t & 1;
    *(i64*)(xq + ((size_t)bd * HP + h) * PLANE + (size_t)g * WP * 8
            + (size_t)(wsel ? 321 : 0) * 8) = 0;
  }
}

__global__ __launch_bounds__(256) void qx_kernel(const float* __restrict__ x,
                                                 unsigned char* __restrict__ xq) {
  __shared__ unsigned char lt[64 * 132];
  const int tid = threadIdx.x;
  const int b = blockIdx.z >> 2, d = blockIdx.z & 3;
  const int h = blockIdx.y;
  const int w0 = blockIdx.x * 64;
  const int wl = tid & 63, cig = tid >> 6;
  const size_t cstr = (size_t)Dd * Hh * Ww;
  const float* xp = x + (((size_t)b * Cc * Dd + d) * Hh + h) * Ww + w0 + wl;
  #pragma unroll 4
  for (int i = 0; i < 32; ++i) {
    int ci = cig * 32 + i;
    __hip_fp8_e4m3 q(xp[ci * cstr]);
    lt[wl * 132 + ci] = q.__x;
  }
  __syncthreads();
  unsigned char* plane = xq + ((size_t)(b * Dd + d) * HP + h + 1) * PLANE;
  #pragma unroll
  for (int k = 0; k < 2; ++k) {
    int i = tid + k * 256;
    int g = i >> 5;
    int wp = (i & 31) * 2;
    i64 lo = *(const i64*)(lt + wp * 132 + g * 8);
    i64 hi = *(const i64*)(lt + (wp + 1) * 132 + g * 8);
    L2v v{lo, hi};
    *(L2v*)(plane + (size_t)g * WP * 8 + (size_t)(w0 + 1 + wp) * 8) = v;
  }
}

__global__ void wpack_kernel(const float* __restrict__ w, unsigned char* __restrict__ wpk) {
  int idx = blockIdx.x * 256 + threadIdx.x;
  if (idx >= Cc * Cc * NTAP) return;
  int tap = idx % NTAP;
  int t = idx / NTAP;
  int ci = t % Cc, co = t / Cc;
  int wv = co >> 5, mf = (co >> 4) & 1, l15 = co & 15;
  __hip_fp8_e4m3 q(w[idx]);
  wpk[((((size_t)tap * 16 + (ci >> 3)) * 4 + wv) * 16 + l15) * 16 + mf * 8 + (ci & 7)] = q.__x;
}

__global__ __launch_bounds__(256, 4) void conv_mfma(const unsigned char* __restrict__ xq,
                                                    const unsigned char* __restrict__ wpk,
                                                    float* __restrict__ out) {
  __shared__ unsigned char lb[48 * 528];           // [kd3][hrow4][g4][66w][8B]
  const int tid = threadIdx.x;
  const int lane = tid & 63, wv = tid >> 6;
  const int l15 = lane & 15, kg = lane >> 4;
  const int b = blockIdx.z >> 2, dout = blockIdx.z & 3;
  const int h0 = blockIdx.y * 2;
  const int w0 = blockIdx.x * 64;
  const int kdmin = dout >= 2 ? 0 : 2 - dout;

  // ---- per-k staging descriptors (cc-invariant; cc adds CCSTEP*cc) ----
  const unsigned char* srcb[NLD];
  int ldsoff[NLD];
  bool vld[NLD];
  #pragma unroll
  for (int k = 0; k < NLD; ++k) {
    int i = kdmin * 528 + tid + k * 256;
    vld[k] = i < 1584;
    int ii = vld[k] ? i : kdmin * 528;
    int row = ii / 33, seg = ii - row * 33;
    int g = row & 3, hrow = (row >> 2) & 3, kd = row >> 4;
    srcb[k] = xq + ((size_t)(b * Dd + dout + kd - 2) * HP + h0 + hrow) * PLANE
              + (size_t)g * WP * 8 + (size_t)w0 * 8 + (size_t)seg * 16;
    ldsoff[k] = ii * 16;
  }

  f32x4 acc[2][2][4];
  #pragma unroll
  for (int a = 0; a < 2; ++a)
    #pragma unroll
    for (int m = 0; m < 2; ++m)
      #pragma unroll
      for (int n = 0; n < 4; ++n) acc[a][m][n] = (f32x4){0.f, 0.f, 0.f, 0.f};

  // ---- prefetch chunk 0 into regs ----
  i64 rx[NLD], ry[NLD];
  #pragma unroll
  for (int k = 0; k < NLD; ++k)
    if (vld[k]) { L2v v = *(const L2v*)srcb[k]; rx[k] = v.x; ry[k] = v.y; }

  for (int cc = 0; cc < 4; ++cc) {
    __syncthreads();                             // all waves done with lb (MFMA phase)
    // ---- write current chunk to LDS (vmcnt wait for prefetch lands here) ----
    #pragma unroll
    for (int k = 0; k < NLD; ++k)
      if (vld[k]) { L2v v{rx[k], ry[k]}; *(L2v*)(lb + ldsoff[k]) = v; }
    // ---- issue next chunk's loads; they fly across the barrier (T14) ----
    if (cc < 3) {
      #pragma unroll
      for (int k = 0; k < NLD; ++k)
        if (vld[k]) {
          L2v v = *(const L2v*)(srcb[k] + (size_t)(cc + 1) * CCSTEP);
          rx[k] = v.x; ry[k] = v.y;
        }
    }
    asm volatile("s_waitcnt lgkmcnt(0)" ::: "memory");  // ds_writes visible; vmcnt untouched
    __builtin_amdgcn_s_barrier();
    __builtin_amdgcn_sched_barrier(0);
    // ---- 27 taps, K=32 per tap ----
    for (int tap = kdmin * 9; tap < NTAP; ++tap) {
      const int kd = tap / 9, khw = tap % 9;
      const int kh = khw / 3, kw = khw % 3;
      L2v av = *(const L2v*)(wpk +
          ((((size_t)tap * 16 + cc * 4 + kg) * 4 + wv) * 16 + l15) * 16);
      #pragma unroll
      for (int hr = 0; hr < 2; ++hr) {
        const unsigned char* bbase = lb + ((kd * 4 + hr + kh) * 4 + kg) * 528 + (l15 + kw) * 8;
        #pragma unroll
        for (int nf = 0; nf < 4; ++nf) {
          i64 bf = *(const i64*)(bbase + nf * 128);
          acc[hr][0][nf] = __builtin_amdgcn_mfma_f32_16x16x32_fp8_fp8(av.x, bf, acc[hr][0][nf], 0, 0, 0);
          acc[hr][1][nf] = __builtin_amdgcn_mfma_f32_16x16x32_fp8_fp8(av.y, bf, acc[hr][1][nf], 0, 0, 0);
        }
      }
    }
  }

  #pragma unroll
  for (int hr = 0; hr < 2; ++hr)
    #pragma unroll
    for (int mf = 0; mf < 2; ++mf)
      #pragma unroll
      for (int nf = 0; nf < 4; ++nf) {
        int ww = w0 + nf * 16 + l15;
        #pragma unroll
        for (int r = 0; r < 4; ++r) {
          int co = wv * 32 + mf * 16 + kg * 4 + r;
          out[(((size_t)b * Cc + co) * Dd + dout) * (size_t)(Hh * Ww)
              + (size_t)(h0 + hr) * Ww + ww] = acc[hr][mf][nf][r];
        }
      }
}

extern "C" void kernel_launch(void* const* d_in, const int* in_sizes, int n_in,
                              void* d_out, int out_size, void* d_ws, size_t ws_size,
                              hipStream_t stream) {
  const float* x = (const float*)d_in[0];
  const float* w = (const float*)d_in[1];
  unsigned char* xq = (unsigned char*)d_ws;
  unsigned char* wpk = xq + XQ_BYTES;
  float* out = (float*)d_out;

  int nz = ZA + ZB;
  zero_pad_kernel<<<(nz + 255) / 256, 256, 0, stream>>>(xq);

  dim3 g1(Ww / 64, Hh, 2 * Dd);
  qx_kernel<<<g1, 256, 0, stream>>>(x, xq);

  int nw = Cc * Cc * NTAP;
  wpack_kernel<<<(nw + 255) / 256, 256, 0, stream>>>(w, wpk);

  dim3 g2(Ww / 64, Hh / 2, 2 * Dd);
  conv_mfma<<<g2, 256, 0, stream>>>(xq, wpk, out);
}

// Round 6
// 265.334 us; speedup vs baseline: 1.0893x; 1.0893x over previous
//
#include <hip/hip_runtime.h>
#include <hip/hip_fp8.h>

// CausalConv3dFP8 round 6: revert T14 (null — TLP already covered it);
// fully-unrolled 9-tap body per kd (imm-offset ds_reads + CSE of duplicate rows),
// batched per-kd A-fragment loads (1 vmcnt wait / 144 MFMAs), T5 setprio.
// xq global layout: [b][d4][hp194][ci8 16][wp322][8B]
// wpk layout:       [tap27][ci8 16][wv4][l15 16][mf2][8B]

using f32x4 = __attribute__((ext_vector_type(4))) float;
typedef long long i64;
struct alignas(16) L2v { i64 x, y; };

namespace {
constexpr int Cc = 128, Dd = 4, Hh = 192, Ww = 320;
constexpr int HP = 194, WP = 322;
constexpr int NTAP = 27;
constexpr size_t PLANE = (size_t)16 * WP * 8;              // 41,216 B per (b,d,h) row-plane
constexpr size_t XQ_BYTES = (size_t)2 * Dd * HP * PLANE;   // 63,967,232
constexpr int ZA = 8 * 2 * 2576;
constexpr int ZB = 8 * 192 * 32;
}

__global__ __launch_bounds__(256) void zero_pad_kernel(unsigned char* __restrict__ xq) {
  int i = blockIdx.x * 256 + threadIdx.x;
  if (i < ZA) {
    int bd = i / (2 * 2576);
    int r = i - bd * (2 * 2576);
    int hsel = r / 2576, seg = r - hsel * 2576;
    L2v z{0, 0};
    *(L2v*)(xq + ((size_t)bd * HP + (hsel ? 193 : 0)) * PLANE + (size_t)seg * 16) = z;
  } else if (i < ZA + ZB) {
    int j = i - ZA;
    int bd = j / (192 * 32);
    int r = j - bd * (192 * 32);
    int h = r / 32 + 1;
    int t = r & 31;
    int g = t >> 1, wsel = t & 1;
    *(i64*)(xq + ((size_t)bd * HP + h) * PLANE + (size_t)g * WP * 8
            + (size_t)(wsel ? 321 : 0) * 8) = 0;
  }
}

__global__ __launch_bounds__(256) void qx_kernel(const float* __restrict__ x,
                                                 unsigned char* __restrict__ xq) {
  __shared__ unsigned char lt[64 * 132];
  const int tid = threadIdx.x;
  const int b = blockIdx.z >> 2, d = blockIdx.z & 3;
  const int h = blockIdx.y;
  const int w0 = blockIdx.x * 64;
  const int wl = tid & 63, cig = tid >> 6;
  const size_t cstr = (size_t)Dd * Hh * Ww;
  const float* xp = x + (((size_t)b * Cc * Dd + d) * Hh + h) * Ww + w0 + wl;
  #pragma unroll 4
  for (int i = 0; i < 32; ++i) {
    int ci = cig * 32 + i;
    __hip_fp8_e4m3 q(xp[ci * cstr]);
    lt[wl * 132 + ci] = q.__x;
  }
  __syncthreads();
  unsigned char* plane = xq + ((size_t)(b * Dd + d) * HP + h + 1) * PLANE;
  #pragma unroll
  for (int k = 0; k < 2; ++k) {
    int i = tid + k * 256;
    int g = i >> 5;
    int wp = (i & 31) * 2;
    i64 lo = *(const i64*)(lt + wp * 132 + g * 8);
    i64 hi = *(const i64*)(lt + (wp + 1) * 132 + g * 8);
    L2v v{lo, hi};
    *(L2v*)(plane + (size_t)g * WP * 8 + (size_t)(w0 + 1 + wp) * 8) = v;
  }
}

__global__ void wpack_kernel(const float* __restrict__ w, unsigned char* __restrict__ wpk) {
  int idx = blockIdx.x * 256 + threadIdx.x;
  if (idx >= Cc * Cc * NTAP) return;
  int tap = idx % NTAP;
  int t = idx / NTAP;
  int ci = t % Cc, co = t / Cc;
  int wv = co >> 5, mf = (co >> 4) & 1, l15 = co & 15;
  __hip_fp8_e4m3 q(w[idx]);
  wpk[((((size_t)tap * 16 + (ci >> 3)) * 4 + wv) * 16 + l15) * 16 + mf * 8 + (ci & 7)] = q.__x;
}

__global__ __launch_bounds__(256, 4) void conv_mfma(const unsigned char* __restrict__ xq,
                                                    const unsigned char* __restrict__ wpk,
                                                    float* __restrict__ out) {
  __shared__ unsigned char lb[48 * 528];           // [kd3][hrow4][g4][66w][8B]
  const int tid = threadIdx.x;
  const int lane = tid & 63, wv = tid >> 6;
  const int l15 = lane & 15, kg = lane >> 4;
  const int b = blockIdx.z >> 2, dout = blockIdx.z & 3;
  const int h0 = blockIdx.y * 2;
  const int w0 = blockIdx.x * 64;
  const int kdmin = dout >= 2 ? 0 : 2 - dout;
  // lane-constant part of the A-fragment address
  const int aoff = kg * 1024 + wv * 256 + l15 * 16;

  f32x4 acc[2][2][4];
  #pragma unroll
  for (int a = 0; a < 2; ++a)
    #pragma unroll
    for (int m = 0; m < 2; ++m)
      #pragma unroll
      for (int n = 0; n < 4; ++n) acc[a][m][n] = (f32x4){0.f, 0.f, 0.f, 0.f};

  for (int cc = 0; cc < 4; ++cc) {
    __syncthreads();
    // ---- stage 48-row B tile (skip kd planes that are causal zeros) ----
    for (int i = tid + kdmin * 528; i < 48 * 33; i += 256) {
      int row = i / 33, seg = i - row * 33;
      int g = row & 3, hrow = (row >> 2) & 3, kd = row >> 4;
      const unsigned char* src = xq
          + ((size_t)(b * Dd + dout + kd - 2) * HP + h0 + hrow) * PLANE
          + (size_t)(cc * 4 + g) * WP * 8 + (size_t)w0 * 8 + (size_t)seg * 16;
      *(L2v*)(lb + row * 528 + seg * 16) = *(const L2v*)src;
    }
    __syncthreads();
    __builtin_amdgcn_s_setprio(1);
    const unsigned char* wcc = wpk + cc * 4096 + aoff;
    for (int kd = kdmin; kd < 3; ++kd) {
      const unsigned char* wb = wcc + (size_t)kd * 9 * 16384;
      const unsigned char* lbase = lb + (kd * 16 + kg) * 528 + l15 * 8;
      // batched A-fragments for this kd-group (9 taps), one vmcnt drain
      L2v av[9];
      #pragma unroll
      for (int t = 0; t < 9; ++t) av[t] = *(const L2v*)(wb + (size_t)t * 16384);
      // fully unrolled 9 taps: imm-offset ds_reads, duplicates CSE'd by compiler
      #pragma unroll
      for (int kh = 0; kh < 3; ++kh)
        #pragma unroll
        for (int hr = 0; hr < 2; ++hr)
          #pragma unroll
          for (int kw = 0; kw < 3; ++kw)
            #pragma unroll
            for (int nf = 0; nf < 4; ++nf) {
              i64 bf = *(const i64*)(lbase + (hr + kh) * 2112 + kw * 8 + nf * 128);
              acc[hr][0][nf] = __builtin_amdgcn_mfma_f32_16x16x32_fp8_fp8(
                  av[kh * 3 + kw].x, bf, acc[hr][0][nf], 0, 0, 0);
              acc[hr][1][nf] = __builtin_amdgcn_mfma_f32_16x16x32_fp8_fp8(
                  av[kh * 3 + kw].y, bf, acc[hr][1][nf], 0, 0, 0);
            }
    }
    __builtin_amdgcn_s_setprio(0);
  }

  #pragma unroll
  for (int hr = 0; hr < 2; ++hr)
    #pragma unroll
    for (int mf = 0; mf < 2; ++mf)
      #pragma unroll
      for (int nf = 0; nf < 4; ++nf) {
        int ww = w0 + nf * 16 + l15;
        #pragma unroll
        for (int r = 0; r < 4; ++r) {
          int co = wv * 32 + mf * 16 + kg * 4 + r;
          out[(((size_t)b * Cc + co) * Dd + dout) * (size_t)(Hh * Ww)
              + (size_t)(h0 + hr) * Ww + ww] = acc[hr][mf][nf][r];
        }
      }
}

extern "C" void kernel_launch(void* const* d_in, const int* in_sizes, int n_in,
                              void* d_out, int out_size, void* d_ws, size_t ws_size,
                              hipStream_t stream) {
  const float* x = (const float*)d_in[0];
  const float* w = (const float*)d_in[1];
  unsigned char* xq = (unsigned char*)d_ws;
  unsigned char* wpk = xq + XQ_BYTES;
  float* out = (float*)d_out;

  int nz = ZA + ZB;
  zero_pad_kernel<<<(nz + 255) / 256, 256, 0, stream>>>(xq);

  dim3 g1(Ww / 64, Hh, 2 * Dd);
  qx_kernel<<<g1, 256, 0, stream>>>(x, xq);

  int nw = Cc * Cc * NTAP;
  wpack_kernel<<<(nw + 255) / 256, 256, 0, stream>>>(w, wpk);

  dim3 g2(Ww / 64, Hh / 2, 2 * Dd);
  conv_mfma<<<g2, 256, 0, stream>>>(xq, wpk, out);
}

// Round 7
// 247.619 us; speedup vs baseline: 1.1672x; 1.0715x over previous
//
#include <hip/hip_runtime.h>
#include <hip/hip_fp8.h>

// CausalConv3dFP8 round 7: MX-scaled fp8 MFMA (scale=1.0 exact) — 32x32x64 f8f6f4,
// 2.3x the non-scaled fp8 rate. K-chunks of 64 ci, 32B B-frags from swizzled LDS,
// 32B A-frags fragment-linear in ws. kd-skip kept.
// xq layout: [b][d4][hp194][ci32 grp 4][wp322][32B]
// wpk layout: [tap27][cc2][ct4][lane64][32B]

using f32x16 = __attribute__((ext_vector_type(16))) float;
using i32x8 = __attribute__((ext_vector_type(8))) int;
typedef long long i64;
struct alignas(16) L2v { i64 x, y; };

namespace {
constexpr int Cc = 128, Dd = 4, Hh = 192, Ww = 320;
constexpr int HP = 194, WP = 322;
constexpr int NTAP = 27;
constexpr size_t PLANE = (size_t)4 * WP * 32;               // 41,216 B per (b,d,h) row-plane
constexpr size_t XQ_BYTES = (size_t)2 * Dd * HP * PLANE;    // 63,967,232
constexpr int ZA = 8 * 2 * 2576;                            // h-border 16B units
constexpr int ZB = 8 * 192 * 32;                            // w-border i64 units
constexpr int GSTR = WP * 32;                               // 10,304 B per ci32-group
}

__global__ __launch_bounds__(256) void zero_pad_kernel(unsigned char* __restrict__ xq) {
  int i = blockIdx.x * 256 + threadIdx.x;
  if (i < ZA) {                                   // h = 0 / h = 193 full planes
    int bd = i / (2 * 2576);
    int r = i - bd * (2 * 2576);
    int hsel = r / 2576, seg = r - hsel * 2576;
    L2v z{0, 0};
    *(L2v*)(xq + ((size_t)bd * HP + (hsel ? 193 : 0)) * PLANE + (size_t)seg * 16) = z;
  } else if (i < ZA + ZB) {                       // w = 0 / w = 321 columns
    int j = i - ZA;
    int bd = j / (192 * 32);
    int r = j - bd * (192 * 32);
    int h = r / 32 + 1;
    int t = r & 31;
    int g = t >> 3, s2 = t & 7;
    int wsel = s2 >> 2, part = s2 & 3;
    *(i64*)(xq + ((size_t)bd * HP + h) * PLANE + (size_t)g * GSTR
            + (size_t)(wsel ? 321 : 0) * 32 + part * 8) = 0;
  }
}

__global__ __launch_bounds__(256) void qx_kernel(const float* __restrict__ x,
                                                 unsigned char* __restrict__ xq) {
  __shared__ unsigned char lt[64 * 136];          // [w][ci], pitch 136 (8-aligned rows)
  const int tid = threadIdx.x;
  const int b = blockIdx.z >> 2, d = blockIdx.z & 3;
  const int h = blockIdx.y;
  const int w0 = blockIdx.x * 64;
  const int wl = tid & 63, cig = tid >> 6;
  const size_t cstr = (size_t)Dd * Hh * Ww;
  const float* xp = x + (((size_t)b * Cc * Dd + d) * Hh + h) * Ww + w0 + wl;
  #pragma unroll 4
  for (int i = 0; i < 32; ++i) {
    int ci = cig * 32 + i;
    __hip_fp8_e4m3 q(xp[ci * cstr]);
    lt[wl * 136 + ci] = q.__x;
  }
  __syncthreads();
  unsigned char* plane = xq + ((size_t)(b * Dd + d) * HP + h + 1) * PLANE;
  {
    int g = tid >> 6, w = tid & 63;               // one 32B unit per thread
    const unsigned char* src = lt + w * 136 + g * 32;
    i64 a0 = *(const i64*)(src), a1 = *(const i64*)(src + 8);
    i64 a2 = *(const i64*)(src + 16), a3 = *(const i64*)(src + 24);
    unsigned char* dst = plane + (size_t)g * GSTR + (size_t)(w0 + 1 + w) * 32;
    *(L2v*)dst = L2v{a0, a1};
    *(L2v*)(dst + 16) = L2v{a2, a3};
  }
}

__global__ void wpack_kernel(const float* __restrict__ w, unsigned char* __restrict__ wpk) {
  int idx = blockIdx.x * 256 + threadIdx.x;
  if (idx >= Cc * Cc * NTAP) return;
  int tap = idx % NTAP;
  int t = idx / NTAP;
  int ci = t % Cc, co = t / Cc;
  int cc = ci >> 6, ct = co >> 5;
  int lane = (((ci >> 5) & 1) << 5) | (co & 31);
  __hip_fp8_e4m3 q(w[idx]);
  wpk[((((size_t)tap * 2 + cc) * 4 + ct) * 64 + lane) * 32 + (ci & 31)] = q.__x;
}

__global__ __launch_bounds__(256, 3) void conv_mfma(const unsigned char* __restrict__ xq,
                                                    const unsigned char* __restrict__ wpk,
                                                    float* __restrict__ out) {
  __shared__ unsigned char lb[24 * 2112];         // [kd3][hrow4][cihalf2][66w][32B] = 50,688 B
  const int tid = threadIdx.x;
  const int lane = tid & 63, wv = tid >> 6;
  const int l31 = lane & 31, chalf = lane >> 5;
  const int hr = wv >> 1, ch = wv & 1;            // wave: output h-row, cout-half
  const int b = blockIdx.z >> 2, dout = blockIdx.z & 3;
  const int h0 = blockIdx.y * 2;
  const int w0 = blockIdx.x * 64;
  const int kdmin = dout >= 2 ? 0 : 2 - dout;

  f32x16 acc[2][2];                               // [ct][nf]
  #pragma unroll
  for (int a = 0; a < 2; ++a)
    #pragma unroll
    for (int n = 0; n < 2; ++n)
      #pragma unroll
      for (int r = 0; r < 16; ++r) acc[a][n][r] = 0.f;

  for (int cc = 0; cc < 2; ++cc) {
    __syncthreads();
    // ---- stage [kd][hrow][chalf][66w] 32B units, XOR-swizzled chunks ----
    for (int u = tid + kdmin * 528; u < 1584; u += 256) {
      int w = u % 66;
      int rest = u / 66;
      int chf = rest & 1, rest2 = rest >> 1;
      int hrow = rest2 & 3, kd = rest2 >> 2;
      const unsigned char* src = xq
          + ((size_t)(b * Dd + dout + kd - 2) * HP + h0 + hrow) * PLANE
          + (size_t)(cc * 2 + chf) * GSTR + (size_t)(w0 + w) * 32;
      L2v lo = *(const L2v*)src;
      L2v hi = *(const L2v*)(src + 16);
      int t = (w >> 2) & 1;
      unsigned char* base = lb + rest * 2112;
      *(L2v*)(base + (2 * w + t) * 16) = lo;
      *(L2v*)(base + (2 * w + 1 - t) * 16) = hi;
    }
    __syncthreads();
    __builtin_amdgcn_s_setprio(1);
    for (int kd = kdmin; kd < 3; ++kd) {
      #pragma unroll
      for (int kh = 0; kh < 3; ++kh) {
        // batched A-fragments: 3 kw x 2 ct, 32B each
        i32x8 av[3][2];
        #pragma unroll
        for (int kw = 0; kw < 3; ++kw)
          #pragma unroll
          for (int ct = 0; ct < 2; ++ct) {
            const unsigned char* ap = wpk +
                ((((size_t)(kd * 9 + kh * 3 + kw) * 2 + cc) * 4 + ch * 2 + ct) * 64 + lane) * 32;
            int4 alo = *(const int4*)ap;
            int4 ahi = *(const int4*)(ap + 16);
            av[kw][ct][0] = alo.x; av[kw][ct][1] = alo.y;
            av[kw][ct][2] = alo.z; av[kw][ct][3] = alo.w;
            av[kw][ct][4] = ahi.x; av[kw][ct][5] = ahi.y;
            av[kw][ct][6] = ahi.z; av[kw][ct][7] = ahi.w;
          }
        const unsigned char* pbase = lb + (((kd * 4 + hr + kh) * 2 + chalf)) * 2112;
        #pragma unroll
        for (int kw = 0; kw < 3; ++kw)
          #pragma unroll
          for (int nf = 0; nf < 2; ++nf) {
            int wl = nf * 32 + l31 + kw;          // LDS w index 0..65
            int t = (wl >> 2) & 1;
            int4 blo = *(const int4*)(pbase + (2 * wl + t) * 16);
            int4 bhi = *(const int4*)(pbase + (2 * wl + 1 - t) * 16);
            i32x8 bv;
            bv[0] = blo.x; bv[1] = blo.y; bv[2] = blo.z; bv[3] = blo.w;
            bv[4] = bhi.x; bv[5] = bhi.y; bv[6] = bhi.z; bv[7] = bhi.w;
            #pragma unroll
            for (int ct = 0; ct < 2; ++ct)
              acc[ct][nf] = __builtin_amdgcn_mfma_scale_f32_32x32x64_f8f6f4(
                  av[kw][ct], bv, acc[ct][nf], 0, 0, 0, 127, 0, 127);
          }
      }
    }
    __builtin_amdgcn_s_setprio(0);
  }

  // ---- epilogue: col=lane&31 -> w, row=(reg&3)+8*(reg>>2)+4*chalf -> cout ----
  #pragma unroll
  for (int ct = 0; ct < 2; ++ct)
    #pragma unroll
    for (int nf = 0; nf < 2; ++nf) {
      int ww = w0 + nf * 32 + l31;
      #pragma unroll
      for (int reg = 0; reg < 16; ++reg) {
        int co = ch * 64 + ct * 32 + (reg & 3) + 8 * (reg >> 2) + 4 * chalf;
        out[(((size_t)b * Cc + co) * Dd + dout) * (size_t)(Hh * Ww)
            + (size_t)(h0 + hr) * Ww + ww] = acc[ct][nf][reg];
      }
    }
}

extern "C" void kernel_launch(void* const* d_in, const int* in_sizes, int n_in,
                              void* d_out, int out_size, void* d_ws, size_t ws_size,
                              hipStream_t stream) {
  const float* x = (const float*)d_in[0];
  const float* w = (const float*)d_in[1];
  unsigned char* xq = (unsigned char*)d_ws;
  unsigned char* wpk = xq + XQ_BYTES;             // 442,368 B
  float* out = (float*)d_out;

  int nz = ZA + ZB;
  zero_pad_kernel<<<(nz + 255) / 256, 256, 0, stream>>>(xq);

  dim3 g1(Ww / 64, Hh, 2 * Dd);
  qx_kernel<<<g1, 256, 0, stream>>>(x, xq);

  int nw = Cc * Cc * NTAP;
  wpack_kernel<<<(nw + 255) / 256, 256, 0, stream>>>(w, wpk);

  dim3 g2(Ww / 64, Hh / 2, 2 * Dd);
  conv_mfma<<<g2, 256, 0, stream>>>(xq, wpk, out);
}

// Round 8
// 238.359 us; speedup vs baseline: 1.2126x; 1.0388x over previous
//
#include <hip/hip_runtime.h>
#include <hip/hip_fp8.h>

// CausalConv3dFP8 round 8: MX fp8 32x32x64, 8-wave blocks (acc 64->32 AGPR) for
// 16 waves/CU occupancy; kd-outer staging (33.8KB LDS); imm-offset ds_reads off
// 6 precomputed swizzled bases; bijective XCD h-band swizzle for L2 locality.
// xq layout: [b][d4][hp194][ci32 grp 4][wp322][32B]
// wpk layout: [tap27][cc2][cq4][lane64][32B]

using f32x16 = __attribute__((ext_vector_type(16))) float;
using i32x8 = __attribute__((ext_vector_type(8))) int;
typedef long long i64;
struct alignas(16) L2v { i64 x, y; };

namespace {
constexpr int Cc = 128, Dd = 4, Hh = 192, Ww = 320;
constexpr int HP = 194, WP = 322;
constexpr int NTAP = 27;
constexpr size_t PLANE = (size_t)4 * WP * 32;               // 41,216 B per (b,d,h) row-plane
constexpr size_t XQ_BYTES = (size_t)2 * Dd * HP * PLANE;    // 63,967,232
constexpr int ZA = 8 * 2 * 2576;
constexpr int ZB = 8 * 192 * 32;
constexpr int GSTR = WP * 32;                               // 10,304 B per ci32-group
}

__global__ __launch_bounds__(256) void zero_pad_kernel(unsigned char* __restrict__ xq) {
  int i = blockIdx.x * 256 + threadIdx.x;
  if (i < ZA) {
    int bd = i / (2 * 2576);
    int r = i - bd * (2 * 2576);
    int hsel = r / 2576, seg = r - hsel * 2576;
    L2v z{0, 0};
    *(L2v*)(xq + ((size_t)bd * HP + (hsel ? 193 : 0)) * PLANE + (size_t)seg * 16) = z;
  } else if (i < ZA + ZB) {
    int j = i - ZA;
    int bd = j / (192 * 32);
    int r = j - bd * (192 * 32);
    int h = r / 32 + 1;
    int t = r & 31;
    int g = t >> 3, s2 = t & 7;
    int wsel = s2 >> 2, part = s2 & 3;
    *(i64*)(xq + ((size_t)bd * HP + h) * PLANE + (size_t)g * GSTR
            + (size_t)(wsel ? 321 : 0) * 32 + part * 8) = 0;
  }
}

__global__ __launch_bounds__(256) void qx_kernel(const float* __restrict__ x,
                                                 unsigned char* __restrict__ xq) {
  __shared__ unsigned char lt[64 * 136];
  const int tid = threadIdx.x;
  const int b = blockIdx.z >> 2, d = blockIdx.z & 3;
  const int h = blockIdx.y;
  const int w0 = blockIdx.x * 64;
  const int wl = tid & 63, cig = tid >> 6;
  const size_t cstr = (size_t)Dd * Hh * Ww;
  const float* xp = x + (((size_t)b * Cc * Dd + d) * Hh + h) * Ww + w0 + wl;
  #pragma unroll 4
  for (int i = 0; i < 32; ++i) {
    int ci = cig * 32 + i;
    __hip_fp8_e4m3 q(xp[ci * cstr]);
    lt[wl * 136 + ci] = q.__x;
  }
  __syncthreads();
  unsigned char* plane = xq + ((size_t)(b * Dd + d) * HP + h + 1) * PLANE;
  {
    int g = tid >> 6, w = tid & 63;
    const unsigned char* src = lt + w * 136 + g * 32;
    i64 a0 = *(const i64*)(src), a1 = *(const i64*)(src + 8);
    i64 a2 = *(const i64*)(src + 16), a3 = *(const i64*)(src + 24);
    unsigned char* dst = plane + (size_t)g * GSTR + (size_t)(w0 + 1 + w) * 32;
    *(L2v*)dst = L2v{a0, a1};
    *(L2v*)(dst + 16) = L2v{a2, a3};
  }
}

__global__ void wpack_kernel(const float* __restrict__ w, unsigned char* __restrict__ wpk) {
  int idx = blockIdx.x * 256 + threadIdx.x;
  if (idx >= Cc * Cc * NTAP) return;
  int tap = idx % NTAP;
  int t = idx / NTAP;
  int ci = t % Cc, co = t / Cc;
  int cc = ci >> 6, cq = co >> 5;
  int lane = (((ci >> 5) & 1) << 5) | (co & 31);
  __hip_fp8_e4m3 q(w[idx]);
  wpk[((((size_t)tap * 2 + cc) * 4 + cq) * 64 + lane) * 32 + (ci & 31)] = q.__x;
}

__global__ __launch_bounds__(512, 4) void conv_mfma(const unsigned char* __restrict__ xq,
                                                    const unsigned char* __restrict__ wpk,
                                                    float* __restrict__ out) {
  __shared__ unsigned char lb[16 * 2112];          // [hrow4][g4][66w][32B] = 33,792 B
  const int tid = threadIdx.x;
  const int lane = tid & 63, wv = tid >> 6;
  const int l31 = lane & 31, chalf = lane >> 5;
  const int hr = wv >> 2, ch = wv & 3;             // wave: h-row, cout-quarter
  // ---- bijective XCD h-band swizzle: xcd owns h0 band [xcd*24, +24) ----
  const int id = blockIdx.x;
  const int xcd = id & 7, j = id >> 3;
  const int h0l = j / 40, rem = j - h0l * 40;
  const int z = rem / 5, wx = rem - z * 5;
  const int b = z >> 2, dout = z & 3;
  const int h0 = (xcd * 12 + h0l) * 2;
  const int w0 = wx * 64;
  const int kdmin = dout >= 2 ? 0 : 2 - dout;

  // ---- 6 swizzled B-read bases (all later ds_reads are imm-offset) ----
  const unsigned char* bbl[3];
  const unsigned char* bbh[3];
  {
    unsigned char* rbase = lb + (hr * 4 + chalf) * 2112;
    #pragma unroll
    for (int kw = 0; kw < 3; ++kw) {
      int wl = l31 + kw;
      int t = (wl >> 2) & 1;
      bbl[kw] = rbase + 32 * wl + 16 * t;
      bbh[kw] = rbase + 32 * wl + 16 * (1 - t);
    }
  }

  f32x16 acc[2];
  #pragma unroll
  for (int n = 0; n < 2; ++n)
    #pragma unroll
    for (int r = 0; r < 16; ++r) acc[n][r] = 0.f;

  for (int kd = kdmin; kd < 3; ++kd) {
    __syncthreads();
    // ---- stage all 128 ci for this kd: 1056 x 32B units ----
    #pragma unroll
    for (int it = 0; it < 3; ++it) {
      int u = tid + it * 512;
      if (u < 1056) {
        int w = u % 66, rest = u / 66;
        int g = rest & 3, hrow = rest >> 2;
        const unsigned char* src = xq
            + ((size_t)(b * Dd + dout + kd - 2) * HP + h0 + hrow) * PLANE
            + (size_t)g * GSTR + (size_t)(w0 + w) * 32;
        L2v lo = *(const L2v*)src;
        L2v hi = *(const L2v*)(src + 16);
        int t = (w >> 2) & 1;
        unsigned char* base = lb + rest * 2112;
        *(L2v*)(base + (2 * w + t) * 16) = lo;
        *(L2v*)(base + (2 * w + 1 - t) * 16) = hi;
      }
    }
    __syncthreads();
    __builtin_amdgcn_s_setprio(1);
    #pragma unroll
    for (int kh = 0; kh < 3; ++kh)
      #pragma unroll
      for (int cc = 0; cc < 2; ++cc) {
        i32x8 av[3];
        #pragma unroll
        for (int kw = 0; kw < 3; ++kw) {
          const unsigned char* ap = wpk +
              ((((size_t)(kd * 9 + kh * 3 + kw) * 2 + cc) * 4 + ch) * 64 + lane) * 32;
          int4 alo = *(const int4*)ap;
          int4 ahi = *(const int4*)(ap + 16);
          av[kw][0] = alo.x; av[kw][1] = alo.y; av[kw][2] = alo.z; av[kw][3] = alo.w;
          av[kw][4] = ahi.x; av[kw][5] = ahi.y; av[kw][6] = ahi.z; av[kw][7] = ahi.w;
        }
        #pragma unroll
        for (int kw = 0; kw < 3; ++kw)
          #pragma unroll
          for (int nf = 0; nf < 2; ++nf) {
            const int off = (kh * 4 + cc * 2) * 2112 + nf * 1024;   // compile-time imm
            int4 blo = *(const int4*)(bbl[kw] + off);
            int4 bhi = *(const int4*)(bbh[kw] + off);
            i32x8 bv;
            bv[0] = blo.x; bv[1] = blo.y; bv[2] = blo.z; bv[3] = blo.w;
            bv[4] = bhi.x; bv[5] = bhi.y; bv[6] = bhi.z; bv[7] = bhi.w;
            acc[nf] = __builtin_amdgcn_mfma_scale_f32_32x32x64_f8f6f4(
                av[kw], bv, acc[nf], 0, 0, 0, 127, 0, 127);
          }
      }
    __builtin_amdgcn_s_setprio(0);
  }

  // ---- epilogue: col=l31 -> w, row=(reg&3)+8*(reg>>2)+4*chalf -> cout ----
  #pragma unroll
  for (int nf = 0; nf < 2; ++nf) {
    int ww = w0 + nf * 32 + l31;
    #pragma unroll
    for (int reg = 0; reg < 16; ++reg) {
      int co = ch * 32 + (reg & 3) + 8 * (reg >> 2) + 4 * chalf;
      out[(((size_t)b * Cc + co) * Dd + dout) * (size_t)(Hh * Ww)
          + (size_t)(h0 + hr) * Ww + ww] = acc[nf][reg];
    }
  }
}

extern "C" void kernel_launch(void* const* d_in, const int* in_sizes, int n_in,
                              void* d_out, int out_size, void* d_ws, size_t ws_size,
                              hipStream_t stream) {
  const float* x = (const float*)d_in[0];
  const float* w = (const float*)d_in[1];
  unsigned char* xq = (unsigned char*)d_ws;
  unsigned char* wpk = xq + XQ_BYTES;              // 442,368 B
  float* out = (float*)d_out;

  int nz = ZA + ZB;
  zero_pad_kernel<<<(nz + 255) / 256, 256, 0, stream>>>(xq);

  dim3 g1(Ww / 64, Hh, 2 * Dd);
  qx_kernel<<<g1, 256, 0, stream>>>(x, xq);

  int nw = Cc * Cc * NTAP;
  wpack_kernel<<<(nw + 255) / 256, 256, 0, stream>>>(w, wpk);

  conv_mfma<<<dim3(3840), 512, 0, stream>>>(xq, wpk, out);
}

// Round 9
// 235.425 us; speedup vs baseline: 1.2277x; 1.0125x over previous
//
#include <hip/hip_runtime.h>
#include <hip/hip_fp8.h>

// CausalConv3dFP8 round 9: MX fp8 32x32x64. Wave tile 2ct x 2nf (64co x 64w):
// per MFMA = 1024B LDS (B) + 1024B L1 (A) — both pipes at ~MFMA rate.
// Split-half LDS [hrow][g][half][66w][16B]: all ds ops lane-stride-16B, conflict-free.
// kd-outer staging, bijective XCD h-band swizzle, kd-skip. 256 thr, 4 blocks/CU.
// xq layout: [b][d4][hp194][ci32 grp 4][wp322][32B]
// wpk layout: [tap27][cc2][cq4 = ch*2+ct][lane64][32B]

using f32x16 = __attribute__((ext_vector_type(16))) float;
using i32x8 = __attribute__((ext_vector_type(8))) int;
typedef long long i64;
struct alignas(16) L2v { i64 x, y; };

namespace {
constexpr int Cc = 128, Dd = 4, Hh = 192, Ww = 320;
constexpr int HP = 194, WP = 322;
constexpr int NTAP = 27;
constexpr size_t PLANE = (size_t)4 * WP * 32;               // 41,216 B per (b,d,h) row-plane
constexpr size_t XQ_BYTES = (size_t)2 * Dd * HP * PLANE;    // 63,967,232
constexpr int ZA = 8 * 2 * 2576;
constexpr int ZB = 8 * 192 * 32;
constexpr int GSTR = WP * 32;                               // 10,304 B per ci32-group
constexpr int HB = 1056;                                    // 66*16: half-plane stride in LDS
}

__global__ __launch_bounds__(256) void zero_pad_kernel(unsigned char* __restrict__ xq) {
  int i = blockIdx.x * 256 + threadIdx.x;
  if (i < ZA) {
    int bd = i / (2 * 2576);
    int r = i - bd * (2 * 2576);
    int hsel = r / 2576, seg = r - hsel * 2576;
    L2v z{0, 0};
    *(L2v*)(xq + ((size_t)bd * HP + (hsel ? 193 : 0)) * PLANE + (size_t)seg * 16) = z;
  } else if (i < ZA + ZB) {
    int j = i - ZA;
    int bd = j / (192 * 32);
    int r = j - bd * (192 * 32);
    int h = r / 32 + 1;
    int t = r & 31;
    int g = t >> 3, s2 = t & 7;
    int wsel = s2 >> 2, part = s2 & 3;
    *(i64*)(xq + ((size_t)bd * HP + h) * PLANE + (size_t)g * GSTR
            + (size_t)(wsel ? 321 : 0) * 32 + part * 8) = 0;
  }
}

__global__ __launch_bounds__(256) void qx_kernel(const float* __restrict__ x,
                                                 unsigned char* __restrict__ xq) {
  __shared__ unsigned char lt[64 * 136];
  const int tid = threadIdx.x;
  const int b = blockIdx.z >> 2, d = blockIdx.z & 3;
  const int h = blockIdx.y;
  const int w0 = blockIdx.x * 64;
  const int wl = tid & 63, cig = tid >> 6;
  const size_t cstr = (size_t)Dd * Hh * Ww;
  const float* xp = x + (((size_t)b * Cc * Dd + d) * Hh + h) * Ww + w0 + wl;
  #pragma unroll 4
  for (int i = 0; i < 32; ++i) {
    int ci = cig * 32 + i;
    __hip_fp8_e4m3 q(xp[ci * cstr]);
    lt[wl * 136 + ci] = q.__x;
  }
  __syncthreads();
  unsigned char* plane = xq + ((size_t)(b * Dd + d) * HP + h + 1) * PLANE;
  {
    int g = tid >> 6, w = tid & 63;
    const unsigned char* src = lt + w * 136 + g * 32;
    i64 a0 = *(const i64*)(src), a1 = *(const i64*)(src + 8);
    i64 a2 = *(const i64*)(src + 16), a3 = *(const i64*)(src + 24);
    unsigned char* dst = plane + (size_t)g * GSTR + (size_t)(w0 + 1 + w) * 32;
    *(L2v*)dst = L2v{a0, a1};
    *(L2v*)(dst + 16) = L2v{a2, a3};
  }
}

__global__ void wpack_kernel(const float* __restrict__ w, unsigned char* __restrict__ wpk) {
  int idx = blockIdx.x * 256 + threadIdx.x;
  if (idx >= Cc * Cc * NTAP) return;
  int tap = idx % NTAP;
  int t = idx / NTAP;
  int ci = t % Cc, co = t / Cc;
  int cc = ci >> 6, cq = co >> 5;                  // cq = ch*2 + ct (co 32-group)
  int lane = (((ci >> 5) & 1) << 5) | (co & 31);
  __hip_fp8_e4m3 q(w[idx]);
  wpk[((((size_t)tap * 2 + cc) * 4 + cq) * 64 + lane) * 32 + (ci & 31)] = q.__x;
}

__global__ __launch_bounds__(256, 4) void conv_mfma(const unsigned char* __restrict__ xq,
                                                    const unsigned char* __restrict__ wpk,
                                                    float* __restrict__ out) {
  __shared__ unsigned char lb[4 * 4 * 2 * HB];     // [hrow4][g4][half2][66w][16B] = 33,792 B
  const int tid = threadIdx.x;
  const int lane = tid & 63, wv = tid >> 6;
  const int l31 = lane & 31, chalf = lane >> 5;
  const int hr = wv >> 1, ch = wv & 1;             // wave: h-row, cout-half (64 co)
  // ---- bijective XCD h-band swizzle ----
  const int id = blockIdx.x;
  const int xcd = id & 7, j = id >> 3;
  const int h0l = j / 40, rem = j - h0l * 40;
  const int z = rem / 5, wx = rem - z * 5;
  const int b = z >> 2, dout = z & 3;
  const int h0 = (xcd * 12 + h0l) * 2;
  const int w0 = wx * 64;
  const int kdmin = dout >= 2 ? 0 : 2 - dout;

  // per-kw lane base: R0 = (hr*4 + chalf) row-part, +(l31+kw)*16 within half-plane
  const unsigned char* bb[3];
  #pragma unroll
  for (int kw = 0; kw < 3; ++kw)
    bb[kw] = lb + (hr * 4 + chalf) * 2 * HB + (l31 + kw) * 16;

  f32x16 acc[2][2];                                // [ct][nf]
  #pragma unroll
  for (int a = 0; a < 2; ++a)
    #pragma unroll
    for (int n = 0; n < 2; ++n)
      #pragma unroll
      for (int r = 0; r < 16; ++r) acc[a][n][r] = 0.f;

  for (int kd = kdmin; kd < 3; ++kd) {
    __syncthreads();
    // ---- stage all 128 ci for this kd: 1056 x 32B units, split-half ----
    for (int u = tid; u < 1056; u += 256) {
      int w = u % 66, rest = u / 66;
      int g = rest & 3, hrow = rest >> 2;
      const unsigned char* src = xq
          + ((size_t)(b * Dd + dout + kd - 2) * HP + h0 + hrow) * PLANE
          + (size_t)g * GSTR + (size_t)(w0 + w) * 32;
      L2v lo = *(const L2v*)src;
      L2v hi = *(const L2v*)(src + 16);
      unsigned char* base = lb + (hrow * 4 + g) * 2 * HB + w * 16;
      *(L2v*)(base) = lo;                          // half 0: ci 0..15 of group
      *(L2v*)(base + HB) = hi;                     // half 1: ci 16..31
    }
    __syncthreads();
    __builtin_amdgcn_s_setprio(1);
    #pragma unroll
    for (int kh = 0; kh < 3; ++kh)
      #pragma unroll
      for (int cc = 0; cc < 2; ++cc)
        #pragma unroll
        for (int kw = 0; kw < 3; ++kw) {
          // ---- A fragments: 2 ct x 32B from L1/L2 ----
          i32x8 av[2];
          #pragma unroll
          for (int ct = 0; ct < 2; ++ct) {
            const unsigned char* ap = wpk +
                ((((size_t)((kd * 9 + kh * 3 + kw) * 2) + cc) * 4 + ch * 2 + ct) * 64 + lane) * 32;
            int4 alo = *(const int4*)ap;
            int4 ahi = *(const int4*)(ap + 16);
            av[ct][0] = alo.x; av[ct][1] = alo.y; av[ct][2] = alo.z; av[ct][3] = alo.w;
            av[ct][4] = ahi.x; av[ct][5] = ahi.y; av[ct][6] = ahi.z; av[ct][7] = ahi.w;
          }
          #pragma unroll
          for (int nf = 0; nf < 2; ++nf) {
            // imm offset: row-part (kh*4 + cc*2) half-planes + nf w-offset
            const int off = (kh * 4 + cc * 2) * 2 * HB + nf * 32 * 16;
            int4 blo = *(const int4*)(bb[kw] + off);         // half 0
            int4 bhi = *(const int4*)(bb[kw] + off + HB);    // half 1
            i32x8 bv;
            bv[0] = blo.x; bv[1] = blo.y; bv[2] = blo.z; bv[3] = blo.w;
            bv[4] = bhi.x; bv[5] = bhi.y; bv[6] = bhi.z; bv[7] = bhi.w;
            #pragma unroll
            for (int ct = 0; ct < 2; ++ct)
              acc[ct][nf] = __builtin_amdgcn_mfma_scale_f32_32x32x64_f8f6f4(
                  av[ct], bv, acc[ct][nf], 0, 0, 0, 127, 0, 127);
          }
        }
    __builtin_amdgcn_s_setprio(0);
  }

  // ---- epilogue: col=l31 -> w, row=(reg&3)+8*(reg>>2)+4*chalf -> cout ----
  #pragma unroll
  for (int ct = 0; ct < 2; ++ct)
    #pragma unroll
    for (int nf = 0; nf < 2; ++nf) {
      int ww = w0 + nf * 32 + l31;
      #pragma unroll
      for (int reg = 0; reg < 16; ++reg) {
        int co = ch * 64 + ct * 32 + (reg & 3) + 8 * (reg >> 2) + 4 * chalf;
        out[(((size_t)b * Cc + co) * Dd + dout) * (size_t)(Hh * Ww)
            + (size_t)(h0 + hr) * Ww + ww] = acc[ct][nf][reg];
      }
    }
}

extern "C" void kernel_launch(void* const* d_in, const int* in_sizes, int n_in,
                              void* d_out, int out_size, void* d_ws, size_t ws_size,
                              hipStream_t stream) {
  const float* x = (const float*)d_in[0];
  const float* w = (const float*)d_in[1];
  unsigned char* xq = (unsigned char*)d_ws;
  unsigned char* wpk = xq + XQ_BYTES;              // 442,368 B
  float* out = (float*)d_out;

  int nz = ZA + ZB;
  zero_pad_kernel<<<(nz + 255) / 256, 256, 0, stream>>>(xq);

  dim3 g1(Ww / 64, Hh, 2 * Dd);
  qx_kernel<<<g1, 256, 0, stream>>>(x, xq);

  int nw = Cc * Cc * NTAP;
  wpack_kernel<<<(nw + 255) / 256, 256, 0, stream>>>(w, wpk);

  conv_mfma<<<dim3(3840), 256, 0, stream>>>(xq, wpk, out);
}